// Round 10
// baseline (6943.134 us; speedup 1.0000x reference)
//
#include <hip/hip_runtime.h>
#include <math.h>

#define D 768
#define NH 12
#define DH 64
#define DEPTH 12
#define TMAX 197
#define NPATCH 196
#define BATCH 32
#define DFF 3072
#define NC 1000
#define QSTRIDE 2304   // 3*D
#define SCALE 0.125f
#define EPSF 1e-6f
#define MPAD 6400      // padded A-row count for tile staging overreach

typedef __bf16 bf16x8 __attribute__((ext_vector_type(8)));
typedef float f32x4 __attribute__((ext_vector_type(4)));
typedef short sshort8 __attribute__((ext_vector_type(8)));

// ---------------- bf16 split helpers ----------------

__device__ __forceinline__ short f2bf(float x) {
  unsigned u = __float_as_uint(x);
  u = u + 0x7fffu + ((u >> 16) & 1u);
  return (short)(u >> 16);
}
__device__ __forceinline__ float bf2f(short h) {
  return __uint_as_float(((unsigned)(unsigned short)h) << 16);
}
__device__ __forceinline__ void bsplit(float x, short* hp, short* lp) {
  short h = f2bf(x);
  *hp = h;
  *lp = f2bf(x - bf2f(h));
}

// global -> LDS direct copy, 16B per lane. LDS dest must be wave-uniform base.
__device__ __forceinline__ void gll16(const void* g, void* l) {
  __builtin_amdgcn_global_load_lds(
      (const __attribute__((address_space(1))) void*)g,
      (__attribute__((address_space(3))) void*)l, 16, 0, 0);
}

// ---------------- utility ----------------

__device__ __forceinline__ float block_reduce_sum(float v, float* red, int tid) {
  red[tid] = v; __syncthreads();
  #pragma unroll
  for (int o = 128; o > 0; o >>= 1) { if (tid < o) red[tid] += red[tid + o]; __syncthreads(); }
  float r = red[0]; __syncthreads();
  return r;
}

__global__ void fail_kernel(float* out) { out[0] = 1.0e6f; }

__global__ void init_kernel(int* si, float* sf) {
  si[0] = TMAX;  // tok (N+1)
  si[1] = 0;     // prev_mass valid
  si[2] = 0;     // prune flag this layer
  sf[0] = 0.f;   // prev_mass
}

// ---------------- weight split/transpose ----------------
// W f32 [K][N] -> Wpk bf16 [N][2][K]  (hi plane, lo plane; k contiguous)
__global__ void wsplit_t(const float* __restrict__ W, short* __restrict__ Wpk,
                         int K, int N) {
  __shared__ float t[32][33];
  int n0 = blockIdx.x * 32, k0 = blockIdx.y * 32;
  int tid = threadIdx.x;
  int kk = tid >> 3, n4 = (tid & 7) * 4;
  float4 v = *(const float4*)(W + (size_t)(k0 + kk) * N + n0 + n4);
  t[kk][n4] = v.x; t[kk][n4 + 1] = v.y; t[kk][n4 + 2] = v.z; t[kk][n4 + 3] = v.w;
  __syncthreads();
  int nn = tid >> 3, k4 = (tid & 7) * 4;
  short* dh = Wpk + (size_t)(n0 + nn) * 2 * K + k0 + k4;
  short* dl = dh + K;
  #pragma unroll
  for (int c = 0; c < 4; ++c) bsplit(t[k4 + c][nn], &dh[c], &dl[c]);
}

// W f32 [N][K] (already k-contiguous) -> Wpk [N][2][K]
__global__ void wsplit_nt(const float* __restrict__ W, short* __restrict__ Wpk, int K) {
  const float* src = W + (size_t)blockIdx.x * K;
  short* dh = Wpk + (size_t)blockIdx.x * 2 * K;
  short* dl = dh + K;
  for (int k = threadIdx.x; k < K; k += 256) bsplit(src[k], &dh[k], &dl[k]);
}

// ---------------- embed ----------------

__global__ void im2col_kernel(const float* __restrict__ x, short* __restrict__ Impk) {
  int p = blockIdx.x, b = blockIdx.y;
  int py = p / 14, px = p % 14;
  short* dst = Impk + ((size_t)b * NPATCH + p) * 1536;
  for (int k = threadIdx.x; k < D; k += 256) {
    int c = k >> 8; int rem = k & 255; int i = rem >> 4; int j = rem & 15;
    float v = x[(((size_t)b * 3 + c) * 224 + py * 16 + i) * 224 + px * 16 + j];
    bsplit(v, &dst[k], &dst[768 + k]);
  }
}

__global__ void assemble_kernel(const float* __restrict__ PE, const float* __restrict__ cls,
                                const float* __restrict__ pos, float* __restrict__ X) {
  int t = blockIdx.x, b = blockIdx.y; int tid = threadIdx.x;
  float* xp = X + ((size_t)(b * TMAX) + t) * D;
  for (int k = tid; k < D; k += 256) {
    float v = (t == 0) ? cls[k] : PE[((size_t)(b * NPATCH) + (t - 1)) * D + k];
    xp[k] = v + pos[(size_t)t * D + k];
  }
}

// ---------------- layernorm ----------------

__global__ void ln_kernel(const float* __restrict__ Xin, short* __restrict__ XNpk,
                          const float* __restrict__ wgt, const float* __restrict__ bsh,
                          const int* __restrict__ si) {
  int row = blockIdx.x;
  if ((row % TMAX) >= si[0]) return;
  __shared__ float red[256];
  int tid = threadIdx.x;
  const float* xp = Xin + (size_t)row * D;
  float v0 = xp[tid], v1 = xp[tid + 256], v2 = xp[tid + 512];
  float mu = block_reduce_sum(v0 + v1 + v2, red, tid) * (1.0f / 768.0f);
  float d0 = v0 - mu, d1 = v1 - mu, d2 = v2 - mu;
  float var = block_reduce_sum(d0 * d0 + d1 * d1 + d2 * d2, red, tid) * (1.0f / 768.0f);
  float inv = 1.0f / sqrtf(var + EPSF);
  short* op = XNpk + (size_t)row * 1536;
  float y0 = d0 * inv * wgt[tid] + bsh[tid];
  float y1 = d1 * inv * wgt[tid + 256] + bsh[tid + 256];
  float y2 = d2 * inv * wgt[tid + 512] + bsh[tid + 512];
  bsplit(y0, &op[tid], &op[768 + tid]);
  bsplit(y1, &op[tid + 256], &op[768 + tid + 256]);
  bsplit(y2, &op[tid + 512], &op[768 + tid + 512]);
}

__global__ void lnfinal_kernel(const float* __restrict__ X, float* __restrict__ CLSb,
                               const float* __restrict__ wgt, const float* __restrict__ bsh) {
  int b = blockIdx.x; int tid = threadIdx.x;
  __shared__ float red[256];
  const float* xp = X + (size_t)b * TMAX * D;  // row t=0
  float v0 = xp[tid], v1 = xp[tid + 256], v2 = xp[tid + 512];
  float mu = block_reduce_sum(v0 + v1 + v2, red, tid) * (1.0f / 768.0f);
  float d0 = v0 - mu, d1 = v1 - mu, d2 = v2 - mu;
  float var = block_reduce_sum(d0 * d0 + d1 * d1 + d2 * d2, red, tid) * (1.0f / 768.0f);
  float inv = 1.0f / sqrtf(var + EPSF);
  float* op = CLSb + (size_t)b * D;
  op[tid]       = d0 * inv * wgt[tid]       + bsh[tid];
  op[tid + 256] = d1 * inv * wgt[tid + 256] + bsh[tid + 256];
  op[tid + 512] = d2 * inv * wgt[tid + 512] + bsh[tid + 512];
}

// ---------- block-index swizzle ----------
__device__ __forceinline__ void swz_map(int d, int nx, int ny, int wsub,
                                        int& bx, int& by) {
  int q = ny >> 3, r = ny & 7;
  int rows, mb, l;
  int big = (q + 1) * nx;
  if (d < r * big) { int c = d / big; l = d - c * big; rows = q + 1; mb = c * (q + 1); }
  else { int d2 = d - r * big; int sm = q * nx; int c2 = d2 / sm; l = d2 - c2 * sm; rows = q; mb = r * (q + 1) + c2 * q; }
  int wspan = wsub * rows;
  int j = l / wspan; int t = l - j * wspan;
  int ml = t / wsub; int dx = t - ml * wsub;
  bx = j * wsub + dx; by = mb + ml;
}

// ---------------- MFMA GEMM 128x128 (R3-proven: gll16 A+B, 64KB dbuf) ----------
// bf16x3 split emulation of f32. One __syncthreads per K-tile; prefetch of
// tile k+1 issued after barrier, drained by the next barrier. Best-measured
// 2-phase structure (R3 = 6.48ms); used for patch/proj/FC2 (N=768 shapes).

#define GTM 128
#define GTN 128
#define GTK 32

template<int EPI, int SWZ>
__global__ __launch_bounds__(256)
void mgemm_kernel(const short* __restrict__ Apk, const short* __restrict__ Bpk,
                  const float* __restrict__ bias, const float* __restrict__ Rsrc,
                  float* __restrict__ Cf, short* __restrict__ Cpk,
                  int M, int K, int N, int nx, int ny, int wsub) {
  __shared__ char lds[65536];  // 2 buffers x (A 16KB | B 16KB)
  const int tid = threadIdx.x;
  const int ln = tid & 63;
  const int wv = tid >> 6;
  const int wm = wv >> 1, wn = wv & 1;

  int bx, by;
  if (SWZ) swz_map(blockIdx.x, nx, ny, wsub, bx, by);
  else { bx = blockIdx.x % nx; by = blockIdx.x / nx; }

  const int m0 = by * GTM, n0 = bx * GTN;
  const int lm = ln & 15, kc = ln >> 4;
  const size_t rs = 2 * (size_t)K;

  f32x4 acc[4][4];
  f32x4 zv = {0.f, 0.f, 0.f, 0.f};
  #pragma unroll
  for (int i = 0; i < 4; ++i)
    #pragma unroll
    for (int j = 0; j < 4; ++j) acc[i][j] = zv;

  auto stage = [&](int k0, int buf) {
    char* base = lds + (buf << 15);
    #pragma unroll
    for (int i = 0; i < 4; ++i) {
      int s = (i << 8) + tid;          // physical 16B slot index
      int r = s >> 3;                  // row 0..127
      int sl = (s & 7) ^ (r & 7);      // logical slot (inverse swizzle)
      size_t eoff = (size_t)(sl >> 2) * K + (size_t)(k0 + ((sl & 3) << 3));
      int ldsoff = ((i << 8) + (tid & 192)) << 4;  // wave-uniform
      gll16(Apk + (size_t)(m0 + r) * rs + eoff, base + ldsoff);
      gll16(Bpk + (size_t)(n0 + r) * rs + eoff, base + 16384 + ldsoff);
    }
  };

  const int nk = K / GTK;
  stage(0, 0);
  for (int kt = 0; kt < nk; ++kt) {
    __syncthreads();                    // drains vmcnt -> staged tile visible
    if (kt + 1 < nk) stage((kt + 1) * GTK, (kt + 1) & 1);
    const char* pa = lds + ((kt & 1) << 15);
    const char* pb = pa + 16384;
    bf16x8 bh[4], bl[4];
    #pragma unroll
    for (int j = 0; j < 4; ++j) {
      int c = wn * 64 + j * 16 + lm;
      int bo = c * 128 + ((kc ^ (c & 7)) << 4);
      bh[j] = *(const bf16x8*)(pb + bo);
      bl[j] = *(const bf16x8*)(pb + (bo ^ 64));
    }
    #pragma unroll
    for (int i = 0; i < 4; ++i) {
      int r = wm * 64 + i * 16 + lm;
      int ao = r * 128 + ((kc ^ (r & 7)) << 4);
      bf16x8 ah = *(const bf16x8*)(pa + ao);
      bf16x8 al = *(const bf16x8*)(pa + (ao ^ 64));
      #pragma unroll
      for (int j = 0; j < 4; ++j) {
        acc[i][j] = __builtin_amdgcn_mfma_f32_16x16x32_bf16(ah, bh[j], acc[i][j], 0, 0, 0);
        acc[i][j] = __builtin_amdgcn_mfma_f32_16x16x32_bf16(ah, bl[j], acc[i][j], 0, 0, 0);
        acc[i][j] = __builtin_amdgcn_mfma_f32_16x16x32_bf16(al, bh[j], acc[i][j], 0, 0, 0);
      }
    }
  }

  // epilogue: C/D layout col = ln&15, row = (ln>>4)*4 + t
  #pragma unroll
  for (int i = 0; i < 4; ++i) {
    #pragma unroll
    for (int t = 0; t < 4; ++t) {
      int m = m0 + wm * 64 + i * 16 + kc * 4 + t;
      if (m >= M) continue;
      #pragma unroll
      for (int j = 0; j < 4; ++j) {
        int n = n0 + wn * 64 + j * 16 + lm;
        float v = acc[i][j][t] + bias[n];
        if (EPI == 1) v += Rsrc[(size_t)m * N + n];
        if (EPI == 2) {
          v = v * 0.5f * (1.0f + erff(v * 0.70710678118654752f));
          short h = f2bf(v);
          Cpk[(size_t)m * 2 * N + n] = h;
          Cpk[(size_t)m * 2 * N + N + n] = f2bf(v - bf2f(h));
        } else {
          Cf[(size_t)m * N + n] = v;
        }
      }
    }
  }
}

// ---------------- MFMA GEMM 256x256, 8-wave, 4-phase schedule (T3+T4+T5) ----
// R7-verified geometry (staging math, swizzle, epilogue identical; refcheck'd)
// restructured into the phase-interleaved schedule: per K-tile 4 phases, each
// {ds_read 2 A-frag-rows (+B in p0) | issue stage-part for tile k+1 ->
//  s_barrier -> lgkmcnt(0) -> sched_barrier -> setprio(1) -> 24 MFMA ->
//  setprio(0) -> s_barrier}. Staging for k+1 issued in phases 0/1 (>=2 phases
// of latency cover); ONE vmcnt(0) per tile at phase-3 end + barrier (per-wave
// drain, then cross-wave visibility). No __syncthreads in the K-loop -> the
// vmcnt(0)-before-every-barrier drain stall (m233's 72%) is gone.

#define MFMA3(ACC, AH, AL, BH, BL) \
  ACC = __builtin_amdgcn_mfma_f32_16x16x32_bf16(AH, BH, ACC, 0, 0, 0); \
  ACC = __builtin_amdgcn_mfma_f32_16x16x32_bf16(AH, BL, ACC, 0, 0, 0); \
  ACC = __builtin_amdgcn_mfma_f32_16x16x32_bf16(AL, BH, ACC, 0, 0, 0);

#define READ_A(I, AH, AL) \
  { int r_ = wm * 128 + (I) * 16 + lm; int ao_ = r_ * 128 + ((kc ^ (r_ & 7)) << 4); \
    AH = *(const bf16x8*)(pa + ao_); AL = *(const bf16x8*)(pa + (ao_ ^ 64)); }

#define PHASE_MID() \
  __builtin_amdgcn_s_barrier(); \
  asm volatile("s_waitcnt lgkmcnt(0)" ::: "memory"); \
  __builtin_amdgcn_sched_barrier(0); \
  __builtin_amdgcn_s_setprio(1);

#define PHASE_END() \
  __builtin_amdgcn_s_setprio(0); \
  __builtin_amdgcn_s_barrier();

template<int EPI, int SWZ>
__global__ __launch_bounds__(512)
void mgemm256p_kernel(const short* __restrict__ Apk, const short* __restrict__ Bpk,
                      const float* __restrict__ bias, const float* __restrict__ Rsrc,
                      float* __restrict__ Cf, short* __restrict__ Cpk,
                      int M, int K, int N, int nx, int ny, int wsub) {
  __shared__ char lds[131072];  // 2 x (A 32KB | B 32KB)
  const int tid = threadIdx.x;
  const int ln = tid & 63;
  const int wv = tid >> 6;          // 0..7
  const int wm = wv >> 2, wn = wv & 3;

  int bx, by;
  if (SWZ) swz_map(blockIdx.x, nx, ny, wsub, bx, by);
  else { bx = blockIdx.x % nx; by = blockIdx.x / nx; }

  const int m0 = by * 256, n0 = bx * 256;
  const int lm = ln & 15, kc = ln >> 4;
  const size_t rs = 2 * (size_t)K;

  f32x4 acc[8][4];
  f32x4 zv = {0.f, 0.f, 0.f, 0.f};
  #pragma unroll
  for (int i = 0; i < 8; ++i)
    #pragma unroll
    for (int j = 0; j < 4; ++j) acc[i][j] = zv;

  auto stageA = [&](int k0, int buf) {
    char* base = lds + (buf << 16);
    #pragma unroll
    for (int i = 0; i < 4; ++i) {
      int s = (i << 9) + tid;          // physical 16B slot 0..2047
      int r = s >> 3;                  // row 0..255
      int sl = (s & 7) ^ (r & 7);      // logical slot
      size_t eoff = (size_t)(sl >> 2) * K + (size_t)(k0 + ((sl & 3) << 3));
      int ldsoff = ((i << 9) + (tid & 448)) << 4;  // wave-uniform
      gll16(Apk + (size_t)(m0 + r) * rs + eoff, base + ldsoff);
    }
  };
  auto stageB = [&](int k0, int buf) {
    char* base = lds + (buf << 16) + 32768;
    #pragma unroll
    for (int i = 0; i < 4; ++i) {
      int s = (i << 9) + tid;
      int r = s >> 3;
      int sl = (s & 7) ^ (r & 7);
      size_t eoff = (size_t)(sl >> 2) * K + (size_t)(k0 + ((sl & 3) << 3));
      int ldsoff = ((i << 9) + (tid & 448)) << 4;
      gll16(Bpk + (size_t)(n0 + r) * rs + eoff, base + ldsoff);
    }
  };

  const int nk = K / GTK;
  stageA(0, 0);
  stageB(0, 0);
  asm volatile("s_waitcnt vmcnt(0)" ::: "memory");
  __builtin_amdgcn_s_barrier();
  __builtin_amdgcn_sched_barrier(0);

  for (int kt = 0; kt < nk; ++kt) {
    const int cur = kt & 1;
    const char* pa = lds + (cur << 16);
    const char* pb = pa + 32768;
    const bool pf = (kt + 1 < nk);
    const int knext = (kt + 1) * GTK;
    bf16x8 bh[4], bl[4];

    // ---- phase 0: B frags + A rows 0,1 ; issue A-staging for k+1 ----
    {
      #pragma unroll
      for (int j = 0; j < 4; ++j) {
        int c = wn * 64 + j * 16 + lm;
        int bo = c * 128 + ((kc ^ (c & 7)) << 4);
        bh[j] = *(const bf16x8*)(pb + bo);
        bl[j] = *(const bf16x8*)(pb + (bo ^ 64));
      }
      bf16x8 ah0, al0, ah1, al1;
      READ_A(0, ah0, al0);
      READ_A(1, ah1, al1);
      if (pf) stageA(knext, cur ^ 1);
      PHASE_MID();
      #pragma unroll
      for (int j = 0; j < 4; ++j) {
        MFMA3(acc[0][j], ah0, al0, bh[j], bl[j]);
        MFMA3(acc[1][j], ah1, al1, bh[j], bl[j]);
      }
      PHASE_END();
    }
    // ---- phase 1: A rows 2,3 ; issue B-staging for k+1 ----
    {
      bf16x8 ah0, al0, ah1, al1;
      READ_A(2, ah0, al0);
      READ_A(3, ah1, al1);
      if (pf) stageB(knext, cur ^ 1);
      PHASE_MID();
      #pragma unroll
      for (int j = 0; j < 4; ++j) {
        MFMA3(acc[2][j], ah0, al0, bh[j], bl[j]);
        MFMA3(acc[3][j], ah1, al1, bh[j], bl[j]);
      }
      PHASE_END();
    }
    // ---- phase 2: A rows 4,5 ----
    {
      bf16x8 ah0, al0, ah1, al1;
      READ_A(4, ah0, al0);
      READ_A(5, ah1, al1);
      PHASE_MID();
      #pragma unroll
      for (int j = 0; j < 4; ++j) {
        MFMA3(acc[4][j], ah0, al0, bh[j], bl[j]);
        MFMA3(acc[5][j], ah1, al1, bh[j], bl[j]);
      }
      PHASE_END();
    }
    // ---- phase 3: A rows 6,7 ; tile-boundary drain ----
    {
      bf16x8 ah0, al0, ah1, al1;
      READ_A(6, ah0, al0);
      READ_A(7, ah1, al1);
      PHASE_MID();
      #pragma unroll
      for (int j = 0; j < 4; ++j) {
        MFMA3(acc[6][j], ah0, al0, bh[j], bl[j]);
        MFMA3(acc[7][j], ah1, al1, bh[j], bl[j]);
      }
      __builtin_amdgcn_s_setprio(0);
      asm volatile("s_waitcnt vmcnt(0)" ::: "memory");  // own k+1 loads done (issued >=2 phases ago)
      __builtin_amdgcn_s_barrier();                      // all waves drained -> buf[nxt] visible
      __builtin_amdgcn_sched_barrier(0);
    }
  }

  #pragma unroll
  for (int i = 0; i < 8; ++i) {
    #pragma unroll
    for (int t = 0; t < 4; ++t) {
      int m = m0 + wm * 128 + i * 16 + kc * 4 + t;
      if (m >= M) continue;
      #pragma unroll
      for (int j = 0; j < 4; ++j) {
        int n = n0 + wn * 64 + j * 16 + lm;
        float v = acc[i][j][t] + bias[n];
        if (EPI == 1) v += Rsrc[(size_t)m * N + n];
        if (EPI == 2) {
          v = v * 0.5f * (1.0f + erff(v * 0.70710678118654752f));
          short h = f2bf(v);
          Cpk[(size_t)m * 2 * N + n] = h;
          Cpk[(size_t)m * 2 * N + N + n] = f2bf(v - bf2f(h));
        } else {
          Cf[(size_t)m * N + n] = v;
        }
      }
    }
  }
}

// ---------------- f32 GEMM (head only) ----------------

#define BM 128
#define BN 64
#define BK 16

__global__ __launch_bounds__(256, 2)
void gemm_kernel(const float* __restrict__ A, const float* __restrict__ Bw,
                 const float* __restrict__ bias, float* __restrict__ C,
                 int M, int K, int N) {
  __shared__ float As[BK][BM + 4];
  __shared__ float Bs[BK][BN];
  int tid = threadIdx.x;
  int tx = tid & 15;
  int ty = tid >> 4;
  int m0 = blockIdx.y * BM;
  int n0 = blockIdx.x * BN;
  float acc[8][4];
  #pragma unroll
  for (int i = 0; i < 8; ++i)
    #pragma unroll
    for (int j = 0; j < 4; ++j) acc[i][j] = 0.f;
  const int lkA = tid & 15;
  const int lmA = tid >> 4;
  const int lnB = tid & 63;
  const int lkB = tid >> 6;
  for (int k0 = 0; k0 < K; k0 += BK) {
    #pragma unroll
    for (int r = 0; r < 8; ++r) {
      int ml = r * 16 + lmA;
      int m = m0 + ml;
      float va = 0.f;
      if (m < M) va = A[(size_t)m * K + k0 + lkA];
      As[lkA][ml] = va;
    }
    #pragma unroll
    for (int r = 0; r < 4; ++r) {
      int kk = r * 4 + lkB;
      int n = n0 + lnB;
      float vb = 0.f;
      if (n < N) vb = Bw[(size_t)(k0 + kk) * N + n];
      Bs[kk][lnB] = vb;
    }
    __syncthreads();
    #pragma unroll
    for (int kk = 0; kk < BK; ++kk) {
      const float4 b4 = *(const float4*)(&Bs[kk][tx * 4]);
      const float4 a0 = *(const float4*)(&As[kk][ty * 8]);
      const float4 a1 = *(const float4*)(&As[kk][ty * 8 + 4]);
      const float a[8] = {a0.x, a0.y, a0.z, a0.w, a1.x, a1.y, a1.z, a1.w};
      const float bb[4] = {b4.x, b4.y, b4.z, b4.w};
      #pragma unroll
      for (int i = 0; i < 8; ++i)
        #pragma unroll
        for (int j = 0; j < 4; ++j)
          acc[i][j] = fmaf(a[i], bb[j], acc[i][j]);
    }
    __syncthreads();
  }
  #pragma unroll
  for (int i = 0; i < 8; ++i) {
    int m = m0 + ty * 8 + i;
    if (m >= M) continue;
    #pragma unroll
    for (int j = 0; j < 4; ++j) {
      int n = n0 + tx * 4 + j;
      if (n >= N) continue;
      C[(size_t)m * N + n] = acc[i][j] + bias[n];
    }
  }
}

// ---------------- MFMA attention (flash, bf16x3 split) ----------------

#define QT 64
#define KVT 64

__global__ __launch_bounds__(256)
void mattn_kernel(const float* __restrict__ QKV, short* __restrict__ AOpk,
                  const int* __restrict__ si) {
  const int tok = si[0];
  const int bh = blockIdx.x; const int b = bh / NH, h = bh % NH;
  const int q0 = blockIdx.y * QT;
  if (q0 >= tok) return;
  __shared__ short Kh[4096], Kl[4096], Vth[4096], Vtl[4096];  // 8KB each
  __shared__ short Pb[8192];                                   // 4 waves x (hi 1024 | lo 1024)
  const int tid = threadIdx.x;
  const int l = tid & 63, w = tid >> 6;
  const int lm = l & 15, lg = l >> 4;

  // Q fragments (A-layout: row = lm, k(d) = c*32 + lg*8 + j)
  bf16x8 qh[2], ql[2];
  {
    int qrow = q0 + w * 16 + lm;
    if (qrow >= TMAX) qrow = TMAX - 1;
    const float* qp = QKV + (size_t)(b * TMAX + qrow) * QSTRIDE + h * DH + lg * 8;
    #pragma unroll
    for (int c = 0; c < 2; ++c) {
      sshort8 hs, ls;
      #pragma unroll
      for (int j = 0; j < 8; ++j) {
        float v = qp[c * 32 + j];
        short hh = f2bf(v);
        hs[j] = hh;
        ls[j] = f2bf(v - bf2f(hh));
      }
      qh[c] = __builtin_bit_cast(bf16x8, hs);
      ql[c] = __builtin_bit_cast(bf16x8, ls);
    }
  }

  float mrun[4], lrun[4];
  f32x4 oacc[4];
  f32x4 zv = {0.f, 0.f, 0.f, 0.f};
  #pragma unroll
  for (int t = 0; t < 4; ++t) { mrun[t] = -1e30f; lrun[t] = 0.f; }
  #pragma unroll
  for (int j = 0; j < 4; ++j) oacc[j] = zv;

  const int r0 = (tid >> 4) * 4;     // 0..60
  const int td4 = (tid & 15) * 4;    // 0..60

  for (int j0 = 0; j0 < tok; j0 += KVT) {
    // ---- stage K and V^T (hi/lo) ----
    {
      float vbuf[16];
      #pragma unroll
      for (int i = 0; i < 4; ++i) {
        int gr = j0 + r0 + i; if (gr >= TMAX) gr = TMAX - 1;
        const float* kp = QKV + (size_t)(b * TMAX + gr) * QSTRIDE + D + h * DH + td4;
        float4 kv = *(const float4*)kp;
        short4 sh, sl;
        sh.x = f2bf(kv.x); sl.x = f2bf(kv.x - bf2f(sh.x));
        sh.y = f2bf(kv.y); sl.y = f2bf(kv.y - bf2f(sh.y));
        sh.z = f2bf(kv.z); sl.z = f2bf(kv.z - bf2f(sh.z));
        sh.w = f2bf(kv.w); sl.w = f2bf(kv.w - bf2f(sh.w));
        int r = r0 + i;
        int so = r * 64 + (((td4 >> 3) ^ (r & 7)) << 3) + (td4 & 7);
        *(short4*)(Kh + so) = sh;
        *(short4*)(Kl + so) = sl;
        const float* vp = QKV + (size_t)(b * TMAX + gr) * QSTRIDE + 2 * D + h * DH + td4;
        float4 vv = *(const float4*)vp;
        vbuf[i * 4 + 0] = vv.x; vbuf[i * 4 + 1] = vv.y;
        vbuf[i * 4 + 2] = vv.z; vbuf[i * 4 + 3] = vv.w;
      }
      #pragma unroll
      for (int dd = 0; dd < 4; ++dd) {
        int d = td4 + dd;
        short4 sh, sl;
        float c0 = vbuf[dd], c1 = vbuf[4 + dd], c2 = vbuf[8 + dd], c3 = vbuf[12 + dd];
        sh.x = f2bf(c0); sl.x = f2bf(c0 - bf2f(sh.x));
        sh.y = f2bf(c1); sl.y = f2bf(c1 - bf2f(sh.y));
        sh.z = f2bf(c2); sl.z = f2bf(c2 - bf2f(sh.z));
        sh.w = f2bf(c3); sl.w = f2bf(c3 - bf2f(sh.w));
        int so = d * 64 + (((r0 >> 3) ^ (d & 7)) << 3) + (r0 & 7);
        *(short4*)(Vth + so) = sh;
        *(short4*)(Vtl + so) = sl;
      }
    }
    __syncthreads();

    // ---- S = Q K^T (3-product split) ----
    f32x4 sacc[4];
    #pragma unroll
    for (int jk = 0; jk < 4; ++jk) sacc[jk] = zv;
    #pragma unroll
    for (int c = 0; c < 2; ++c) {
      #pragma unroll
      for (int jk = 0; jk < 4; ++jk) {
        int row = jk * 16 + lm;
        int so = row * 64 + (((c * 4 + lg) ^ (row & 7)) << 3);
        bf16x8 kbh = *(const bf16x8*)(Kh + so);
        bf16x8 kbl = *(const bf16x8*)(Kl + so);
        sacc[jk] = __builtin_amdgcn_mfma_f32_16x16x32_bf16(qh[c], kbh, sacc[jk], 0, 0, 0);
        sacc[jk] = __builtin_amdgcn_mfma_f32_16x16x32_bf16(qh[c], kbl, sacc[jk], 0, 0, 0);
        sacc[jk] = __builtin_amdgcn_mfma_f32_16x16x32_bf16(ql[c], kbh, sacc[jk], 0, 0, 0);
      }
    }

    // ---- online softmax ----
    float p[4][4];
    #pragma unroll
    for (int jk = 0; jk < 4; ++jk) {
      bool valid = (j0 + jk * 16 + lm) < tok;
      #pragma unroll
      for (int t = 0; t < 4; ++t)
        p[jk][t] = valid ? sacc[jk][t] * SCALE : -1e30f;
    }
    float mt[4], mnew[4], co[4], rsm[4];
    #pragma unroll
    for (int t = 0; t < 4; ++t) {
      mt[t] = fmaxf(fmaxf(p[0][t], p[1][t]), fmaxf(p[2][t], p[3][t]));
      #pragma unroll
      for (int off = 1; off < 16; off <<= 1)
        mt[t] = fmaxf(mt[t], __shfl_xor(mt[t], off, 16));
      mnew[t] = fmaxf(mrun[t], mt[t]);
      co[t] = expf(mrun[t] - mnew[t]);
      rsm[t] = 0.f;
    }
    #pragma unroll
    for (int jk = 0; jk < 4; ++jk)
      #pragma unroll
      for (int t = 0; t < 4; ++t) {
        p[jk][t] = expf(p[jk][t] - mnew[t]);
        rsm[t] += p[jk][t];
      }
    #pragma unroll
    for (int t = 0; t < 4; ++t) {
      #pragma unroll
      for (int off = 1; off < 16; off <<= 1)
        rsm[t] += __shfl_xor(rsm[t], off, 16);
      lrun[t] = lrun[t] * co[t] + rsm[t];
      mrun[t] = mnew[t];
    }
    #pragma unroll
    for (int jd = 0; jd < 4; ++jd)
      #pragma unroll
      for (int t = 0; t < 4; ++t) oacc[jd][t] *= co[t];

    // ---- P -> per-wave LDS (bf16 hi/lo, A-frag layout) ----
    short* Pw = Pb + w * 2048;
    #pragma unroll
    for (int jk = 0; jk < 4; ++jk)
      #pragma unroll
      for (int t = 0; t < 4; ++t) {
        int q = lg * 4 + t;
        int col = jk * 16 + lm;
        short hh = f2bf(p[jk][t]);
        short hl = f2bf(p[jk][t] - bf2f(hh));
        int so = q * 64 + (((col >> 3) ^ (q & 7)) << 3) + (col & 7);
        Pw[so] = hh;
        Pw[1024 + so] = hl;
      }

    // ---- PV (3-product split) ----
    #pragma unroll
    for (int c = 0; c < 2; ++c) {
      int aro = lm * 64 + (((c * 4 + lg) ^ (lm & 7)) << 3);
      bf16x8 pah = *(const bf16x8*)(Pw + aro);
      bf16x8 pal = *(const bf16x8*)(Pw + 1024 + aro);
      #pragma unroll
      for (int jd = 0; jd < 4; ++jd) {
        int d = jd * 16 + lm;
        int so = d * 64 + (((c * 4 + lg) ^ (d & 7)) << 3);
        bf16x8 vbh = *(const bf16x8*)(Vth + so);
        bf16x8 vbl = *(const bf16x8*)(Vtl + so);
        oacc[jd] = __builtin_amdgcn_mfma_f32_16x16x32_bf16(pah, vbh, oacc[jd], 0, 0, 0);
        oacc[jd] = __builtin_amdgcn_mfma_f32_16x16x32_bf16(pah, vbl, oacc[jd], 0, 0, 0);
        oacc[jd] = __builtin_amdgcn_mfma_f32_16x16x32_bf16(pal, vbh, oacc[jd], 0, 0, 0);
      }
    }
    __syncthreads();
  }

  // ---- store O (split bf16), rows masked to tok ----
  #pragma unroll
  for (int t = 0; t < 4; ++t) {
    int q = q0 + w * 16 + lg * 4 + t;
    if (q >= tok) continue;
    float inv = 1.0f / lrun[t];
    short* op = AOpk + (size_t)(b * TMAX + q) * 1536 + h * DH;
    #pragma unroll
    for (int jd = 0; jd < 4; ++jd) {
      int d = jd * 16 + lm;
      float y = oacc[jd][t] * inv;
      short hh = f2bf(y);
      op[d] = hh;
      op[768 + d] = f2bf(y - bf2f(hh));
    }
  }
}

// cls attention row per (b,h)
__global__ void clsrow_kernel(const float* __restrict__ QKV, float* __restrict__ Pcls,
                              const int* __restrict__ si) {
  int tok = si[0];
  int bh = blockIdx.x; int b = bh / NH, h = bh % NH;
  int tid = threadIdx.x;
  __shared__ float q[DH];
  __shared__ float red[256];
  if (tid < DH) q[tid] = QKV[((size_t)(b * TMAX)) * QSTRIDE + h * DH + tid];
  __syncthreads();
  float sval = -1e30f;
  if (tid < tok) {
    const float* kp = QKV + ((size_t)(b * TMAX) + tid) * QSTRIDE + D + h * DH;
    float a = 0.f;
    #pragma unroll
    for (int dd = 0; dd < DH; ++dd) a = fmaf(q[dd], kp[dd], a);
    sval = a * SCALE;
  }
  red[tid] = sval; __syncthreads();
  #pragma unroll
  for (int o = 128; o > 0; o >>= 1) { if (tid < o) red[tid] = fmaxf(red[tid], red[tid + o]); __syncthreads(); }
  float mx = red[0]; __syncthreads();
  float e = (tid < tok) ? expf(sval - mx) : 0.f;
  red[tid] = e; __syncthreads();
  #pragma unroll
  for (int o = 128; o > 0; o >>= 1) { if (tid < o) red[tid] += red[tid + o]; __syncthreads(); }
  if (tid < tok) Pcls[(size_t)bh * TMAX + tid] = e / red[0];
}

__global__ void aclsmean_kernel(const float* __restrict__ Pcls, float* __restrict__ Acls,
                                const int* __restrict__ si) {
  int tok = si[0]; int b = blockIdx.x; int tid = threadIdx.x;
  if (tid < tok) {
    float s = 0.f;
    #pragma unroll
    for (int h = 0; h < NH; ++h) s += Pcls[((size_t)b * NH + h) * TMAX + tid];
    Acls[b * TMAX + tid] = s * (1.0f / 12.0f);
  }
}

__global__ void vmean_kernel(const float* __restrict__ QKV, float* __restrict__ Vm,
                             const int* __restrict__ si) {
  int tok = si[0];
  int t = blockIdx.x, b = blockIdx.y;
  if (t >= tok) return;
  int d = threadIdx.x;  // 64
  const float* vp = QKV + ((size_t)(b * TMAX + t)) * QSTRIDE + 2 * D;
  float s = 0.f;
  #pragma unroll
  for (int h = 0; h < NH; ++h) s += vp[h * DH + d];
  Vm[((size_t)b * TMAX + t) * DH + d] = s * (1.0f / 12.0f);
}

// ---------------- pruning stats ----------------

__global__ void stats_kernel(const float* __restrict__ Vm, const float* __restrict__ Acls,
                             float* __restrict__ Jbuf, float* __restrict__ Jsum,
                             float* __restrict__ rhot, const int* __restrict__ si) {
  int tok = si[0]; int N = tok - 1;
  if (N <= 16) return;
  int b = blockIdx.x; int tid = threadIdx.x;
  __shared__ float red[256];
  __shared__ float vmean[DH];
  __shared__ float Vn[NPATCH];
  const float* vb = Vm + (size_t)b * TMAX * DH;

  float x0 = 0.f;
  if (tid < DH) { float v = vb[tid]; x0 = v * v; }
  red[tid] = x0; __syncthreads();
  #pragma unroll
  for (int o = 128; o > 0; o >>= 1) { if (tid < o) red[tid] += red[tid + o]; __syncthreads(); }
  if (tid == 0) rhot[b] = 1.0f + Acls[b * TMAX] * sqrtf(red[0]);
  __syncthreads();

  int d = tid & 63, part = tid >> 6;
  float s = 0.f;
  for (int t = 1 + part; t <= N; t += 4) s += vb[(size_t)t * DH + d];
  red[tid] = s; __syncthreads();
  if (tid < DH) vmean[tid] = (red[tid] + red[tid + 64] + red[tid + 128] + red[tid + 192]) / (float)N;
  __syncthreads();

  if (tid < N) {
    const float* vp = vb + (size_t)(tid + 1) * DH;
    float a = 0.f;
    #pragma unroll
    for (int dd = 0; dd < DH; ++dd) { float z = vp[dd] - vmean[dd]; a = fmaf(z, z, a); }
    Vn[tid] = sqrtf(a);
  }
  __syncthreads();

  red[tid] = (tid < N) ? Vn[tid] : 0.f; __syncthreads();
  #pragma unroll
  for (int o = 128; o > 0; o >>= 1) { if (tid < o) red[tid] += red[tid + o]; __syncthreads(); }
  float mu = red[0] / (float)N;
  __syncthreads();
  float dv = (tid < N) ? (Vn[tid] - mu) : 0.f;
  red[tid] = dv * dv; __syncthreads();
  #pragma unroll
  for (int o = 128; o > 0; o >>= 1) { if (tid < o) red[tid] += red[tid + o]; __syncthreads(); }
  float sd = sqrtf(red[0] / (float)(N - 1));
  __syncthreads();

  float Jv = 0.f;
  if (tid < N) {
    float z = (Vn[tid] - mu) / (sd + EPSF);
    z = fmaxf(z, 0.f);
    Jv = Acls[b * TMAX + 1 + tid] * z;
    Jbuf[b * NPATCH + tid] = Jv;
  }
  red[tid] = Jv; __syncthreads();
  #pragma unroll
  for (int o = 128; o > 0; o >>= 1) { if (tid < o) red[tid] += red[tid + o]; __syncthreads(); }
  if (tid == 0) Jsum[b] = red[0];
}

__global__ void decide_kernel(const float* __restrict__ Jbuf, const float* __restrict__ Jsum,
                              const float* __restrict__ rhot, int* __restrict__ keep,
                              int* __restrict__ si, float* __restrict__ sf) {
  int tok = si[0]; int N = tok - 1;
  int tid = threadIdx.x;
  if (N <= 16) { if (tid == 0) si[2] = 0; return; }
  __shared__ float red[256];
  __shared__ float Jms[NPATCH];
  __shared__ int sel[NPATCH];

  red[tid] = (tid < BATCH) ? rhot[tid] : 0.f; __syncthreads();
  #pragma unroll
  for (int o = 128; o > 0; o >>= 1) { if (tid < o) red[tid] += red[tid + o]; __syncthreads(); }
  float rho = red[0] / (float)BATCH; __syncthreads();
  red[tid] = (tid < BATCH) ? Jsum[tid] : 0.f; __syncthreads();
  #pragma unroll
  for (int o = 128; o > 0; o >>= 1) { if (tid < o) red[tid] += red[tid + o]; __syncthreads(); }
  float mass = red[0] / (float)BATCH;
  int prev_valid = si[1];
  float prev = sf[0];
  __syncthreads();

  int N_next = N;
  if (prev_valid) {
    float eta = mass / (prev + EPSF);
    float re = rho * eta;
    re = fminf(fmaxf(re, 0.25f), 4.0f);
    double kr = pow((double)re, -0.01);
    int nn = (int)((double)N * kr);
    N_next = nn > 16 ? nn : 16;
  }
  if (tid == 0) { si[1] = 1; sf[0] = mass; }

  if (N_next < N) {
    if (tid < N) {
      float sJ = 0.f;
      for (int bb = 0; bb < BATCH; ++bb) sJ += Jbuf[bb * NPATCH + tid];
      Jms[tid] = sJ / (float)BATCH;
    }
    __syncthreads();
    if (tid < N) {
      float me = Jms[tid]; int rank = 0;
      for (int s2 = 0; s2 < N; ++s2) {
        float ov = Jms[s2];
        if (ov > me || (ov == me && s2 < tid)) ++rank;
      }
      sel[tid] = (rank < N_next) ? 1 : 0;
    }
    __syncthreads();
    if (tid == 0) {
      int c = 0; keep[c++] = 0;
      for (int t2 = 0; t2 < N; ++t2) if (sel[t2]) keep[c++] = t2 + 1;
      si[0] = N_next + 1;
      si[2] = 1;
    }
  } else {
    if (tid == 0) si[2] = 0;
  }
}

__global__ void gather_kernel(const float* __restrict__ X, float* __restrict__ T,
                              const int* __restrict__ keep, const int* __restrict__ si) {
  if (!si[2]) return;
  int tok = si[0];
  int i = blockIdx.x, b = blockIdx.y;
  if (i >= tok) return;
  int src = keep[i];
  const float* xp = X + ((size_t)(b * TMAX) + src) * D;
  float* tp = T + ((size_t)(b * TMAX) + i) * D;
  int tid = threadIdx.x;
  tp[tid] = xp[tid]; tp[tid + 256] = xp[tid + 256]; tp[tid + 512] = xp[tid + 512];
}

__global__ void copyback_kernel(const float* __restrict__ T, float* __restrict__ X,
                                const int* __restrict__ si) {
  if (!si[2]) return;
  int tok = si[0];
  int i = blockIdx.x, b = blockIdx.y;
  if (i >= tok) return;
  const float* tp = T + ((size_t)(b * TMAX) + i) * D;
  float* xp = X + ((size_t)(b * TMAX) + i) * D;
  int tid = threadIdx.x;
  xp[tid] = tp[tid]; xp[tid + 256] = tp[tid + 256]; xp[tid + 512] = tp[tid + 512];
}

// ---------------- host ----------------

extern "C" void kernel_launch(void* const* d_in, const int* in_sizes, int n_in,
                              void* d_out, int out_size, void* d_ws, size_t ws_size,
                              hipStream_t stream) {
  (void)in_sizes; (void)n_in; (void)out_size;
  const float* x       = (const float*)d_in[0];
  const float* patch_w = (const float*)d_in[1];
  const float* patch_b = (const float*)d_in[2];
  const float* cls_tok = (const float*)d_in[3];
  const float* pos     = (const float*)d_in[4];
  const float* ln1w    = (const float*)d_in[5];
  const float* ln1b    = (const float*)d_in[6];
  const float* qkvw    = (const float*)d_in[7];
  const float* qkvb    = (const float*)d_in[8];
  const float* projw   = (const float*)d_in[9];
  const float* projb   = (const float*)d_in[10];
  const float* ln2w    = (const float*)d_in[11];
  const float* ln2b    = (const float*)d_in[12];
  const float* fc1w    = (const float*)d_in[13];
  const float* fc1b    = (const float*)d_in[14];
  const float* fc2w    = (const float*)d_in[15];
  const float* fc2b    = (const float*)d_in[16];
  const float* normw   = (const float*)d_in[17];
  const float* normb   = (const float*)d_in[18];
  const float* headw   = (const float*)d_in[19];
  const float* headb   = (const float*)d_in[20];
  float* out = (float*)d_out;

  char* w = (char*)d_ws;
  size_t off = 0;
  auto alloc = [&](size_t bytes) -> void* {
    void* p = w + off;
    off += (bytes + 255) & ~(size_t)255;
    return p;
  };
  const size_t MROWS = (size_t)BATCH * TMAX;  // 6304 (MPAD=6400 for staged A bufs)
  float* X    = (float*)alloc(MROWS * D * 4);
  short* XNpk = (short*)alloc((size_t)MPAD * 1536 * 2);
  float* QKV  = (float*)alloc(MROWS * QSTRIDE * 4);   // also embed f32 out
  short* AOpk = (short*)alloc((size_t)MPAD * 1536 * 2);
  short* Hpk  = (short*)alloc((size_t)MPAD * 2 * DFF * 2);   // also Impk / gather TMP
  float* Vm   = (float*)alloc(MROWS * DH * 4);
  float* Pcls = (float*)alloc((size_t)BATCH * NH * TMAX * 4);
  float* Acls = (float*)alloc((size_t)BATCH * TMAX * 4);
  float* Jbuf = (float*)alloc((size_t)BATCH * NPATCH * 4);
  float* Jsum = (float*)alloc(BATCH * 4);
  float* rhot = (float*)alloc(BATCH * 4);
  int*   keep = (int*)alloc(256 * 4);
  int*   si   = (int*)alloc(64 * 4);
  float* sf   = (float*)alloc(64 * 4);
  float* CLS  = (float*)alloc((size_t)BATCH * D * 4);
  short* Wq   = (short*)alloc((size_t)QSTRIDE * 2 * D * 2);
  short* Wp   = (short*)alloc((size_t)D * 2 * D * 2);
  short* W1   = (short*)alloc((size_t)DFF * 2 * D * 2);
  short* W2   = (short*)alloc((size_t)D * 2 * DFF * 2);
  short* Wpat = (short*)alloc((size_t)D * 2 * D * 2);
  short* Impk = Hpk;
  float* TMP  = (float*)Hpk;
  float* Ef32 = QKV;

  if (off > ws_size) {
    fail_kernel<<<1, 1, 0, stream>>>(out);
    return;
  }

  init_kernel<<<1, 1, 0, stream>>>(si, sf);

  // patch embed (M = 6272 = 49*128 exactly)
  im2col_kernel<<<dim3(NPATCH, BATCH), 256, 0, stream>>>(x, Impk);
  wsplit_nt<<<D, 256, 0, stream>>>(patch_w, Wpat, D);
  mgemm_kernel<0, 1><<<6 * 49, 256, 0, stream>>>(
      Impk, Wpat, patch_b, nullptr, Ef32, nullptr, BATCH * NPATCH, D, D, 6, 49, 6);
  assemble_kernel<<<dim3(TMAX, BATCH), 256, 0, stream>>>(Ef32, cls_tok, pos, X);

  for (int l = 0; l < DEPTH; ++l) {
    const float* l1w = ln1w + l * D;
    const float* l1b = ln1b + l * D;
    const float* qw  = qkvw + (size_t)l * D * 3 * D;
    const float* qb  = qkvb + (size_t)l * 3 * D;
    const float* pw  = projw + (size_t)l * D * D;
    const float* pb  = projb + (size_t)l * D;
    const float* l2w = ln2w + l * D;
    const float* l2b = ln2b + l * D;
    const float* f1w = fc1w + (size_t)l * D * DFF;
    const float* f1b = fc1b + (size_t)l * DFF;
    const float* f2w = fc2w + (size_t)l * DFF * D;
    const float* f2b = fc2b + (size_t)l * D;

    wsplit_t<<<dim3(QSTRIDE / 32, D / 32), 256, 0, stream>>>(qw, Wq, D, QSTRIDE);
    wsplit_t<<<dim3(D / 32, D / 32), 256, 0, stream>>>(pw, Wp, D, D);
    wsplit_t<<<dim3(DFF / 32, D / 32), 256, 0, stream>>>(f1w, W1, D, DFF);
    wsplit_t<<<dim3(D / 32, DFF / 32), 256, 0, stream>>>(f2w, W2, DFF, D);

    ln_kernel<<<BATCH * TMAX, 256, 0, stream>>>(X, XNpk, l1w, l1b, si);
    // QKV: 256^2 8-phase kernel (nx=9, ny=25, wsub=3)
    mgemm256p_kernel<0, 1><<<9 * 25, 512, 0, stream>>>(
        XNpk, Wq, qb, nullptr, QKV, nullptr, (int)MROWS, D, QSTRIDE, 9, 25, 3);
    mattn_kernel<<<dim3(BATCH * NH, (TMAX + QT - 1) / QT), 256, 0, stream>>>(QKV, AOpk, si);
    clsrow_kernel<<<BATCH * NH, 256, 0, stream>>>(QKV, Pcls, si);
    aclsmean_kernel<<<BATCH, 256, 0, stream>>>(Pcls, Acls, si);
    vmean_kernel<<<dim3(TMAX, BATCH), 64, 0, stream>>>(QKV, Vm, si);
    mgemm_kernel<1, 1><<<6 * 50, 256, 0, stream>>>(
        AOpk, Wp, pb, X, X, nullptr, (int)MROWS, D, D, 6, 50, 6);
    ln_kernel<<<BATCH * TMAX, 256, 0, stream>>>(X, XNpk, l2w, l2b, si);
    // FC1: 256^2 8-phase kernel (nx=12, ny=25, wsub=4)
    mgemm256p_kernel<2, 1><<<12 * 25, 512, 0, stream>>>(
        XNpk, W1, f1b, nullptr, nullptr, Hpk, (int)MROWS, D, DFF, 12, 25, 4);
    mgemm_kernel<1, 0><<<6 * 50, 256, 0, stream>>>(
        Hpk, W2, f2b, X, X, nullptr, (int)MROWS, DFF, D, 6, 50, 6);
    stats_kernel<<<BATCH, 256, 0, stream>>>(Vm, Acls, Jbuf, Jsum, rhot, si);
    decide_kernel<<<1, 256, 0, stream>>>(Jbuf, Jsum, rhot, keep, si, sf);
    gather_kernel<<<dim3(TMAX, BATCH), 256, 0, stream>>>(X, TMP, keep, si);
    copyback_kernel<<<dim3(TMAX, BATCH), 256, 0, stream>>>(TMP, X, si);
  }

  lnfinal_kernel<<<BATCH, 256, 0, stream>>>(X, CLS, normw, normb);
  gemm_kernel<<<dim3(16, 1), 256, 0, stream>>>(CLS, headw, headb, out, BATCH, D, NC);
}

// Round 11
// 6545.082 us; speedup vs baseline: 1.0608x; 1.0608x over previous
//
#include <hip/hip_runtime.h>
#include <math.h>

#define D 768
#define NH 12
#define DH 64
#define DEPTH 12
#define TMAX 197
#define NPATCH 196
#define BATCH 32
#define DFF 3072
#define NC 1000
#define QSTRIDE 2304   // 3*D
#define QPK 4608       // packed QKV row stride in shorts: [hi 2304 | lo 2304]
#define SCALE 0.125f
#define EPSF 1e-6f
#define MPAD 6400      // padded A-row count for tile staging overreach

typedef __bf16 bf16x8 __attribute__((ext_vector_type(8)));
typedef float f32x4 __attribute__((ext_vector_type(4)));
typedef short sshort8 __attribute__((ext_vector_type(8)));

// ---------------- bf16 split helpers ----------------

__device__ __forceinline__ short f2bf(float x) {
  unsigned u = __float_as_uint(x);
  u = u + 0x7fffu + ((u >> 16) & 1u);
  return (short)(u >> 16);
}
__device__ __forceinline__ float bf2f(short h) {
  return __uint_as_float(((unsigned)(unsigned short)h) << 16);
}
__device__ __forceinline__ void bsplit(float x, short* hp, short* lp) {
  short h = f2bf(x);
  *hp = h;
  *lp = f2bf(x - bf2f(h));
}

// global -> LDS direct copy, 16B per lane. LDS dest must be wave-uniform base.
__device__ __forceinline__ void gll16(const void* g, void* l) {
  __builtin_amdgcn_global_load_lds(
      (const __attribute__((address_space(1))) void*)g,
      (__attribute__((address_space(3))) void*)l, 16, 0, 0);
}

// ---------------- utility ----------------

__device__ __forceinline__ float block_reduce_sum(float v, float* red, int tid) {
  red[tid] = v; __syncthreads();
  #pragma unroll
  for (int o = 128; o > 0; o >>= 1) { if (tid < o) red[tid] += red[tid + o]; __syncthreads(); }
  float r = red[0]; __syncthreads();
  return r;
}

__global__ void fail_kernel(float* out) { out[0] = 1.0e6f; }

__global__ void init_kernel(int* si, float* sf) {
  si[0] = TMAX;  // tok (N+1)
  si[1] = 0;     // prev_mass valid
  si[2] = 0;     // prune flag this layer
  sf[0] = 0.f;   // prev_mass
}

// ---------------- weight split/transpose ----------------
// W f32 [K][N] -> Wpk bf16 [N][2][K]  (hi plane, lo plane; k contiguous)
__global__ void wsplit_t(const float* __restrict__ W, short* __restrict__ Wpk,
                         int K, int N) {
  __shared__ float t[32][33];
  int n0 = blockIdx.x * 32, k0 = blockIdx.y * 32;
  int tid = threadIdx.x;
  int kk = tid >> 3, n4 = (tid & 7) * 4;
  float4 v = *(const float4*)(W + (size_t)(k0 + kk) * N + n0 + n4);
  t[kk][n4] = v.x; t[kk][n4 + 1] = v.y; t[kk][n4 + 2] = v.z; t[kk][n4 + 3] = v.w;
  __syncthreads();
  int nn = tid >> 3, k4 = (tid & 7) * 4;
  short* dh = Wpk + (size_t)(n0 + nn) * 2 * K + k0 + k4;
  short* dl = dh + K;
  #pragma unroll
  for (int c = 0; c < 4; ++c) bsplit(t[k4 + c][nn], &dh[c], &dl[c]);
}

// W f32 [N][K] (already k-contiguous) -> Wpk [N][2][K]
__global__ void wsplit_nt(const float* __restrict__ W, short* __restrict__ Wpk, int K) {
  const float* src = W + (size_t)blockIdx.x * K;
  short* dh = Wpk + (size_t)blockIdx.x * 2 * K;
  short* dl = dh + K;
  for (int k = threadIdx.x; k < K; k += 256) bsplit(src[k], &dh[k], &dl[k]);
}

// ---------------- embed ----------------

__global__ void im2col_kernel(const float* __restrict__ x, short* __restrict__ Impk) {
  int p = blockIdx.x, b = blockIdx.y;
  int py = p / 14, px = p % 14;
  short* dst = Impk + ((size_t)b * NPATCH + p) * 1536;
  for (int k = threadIdx.x; k < D; k += 256) {
    int c = k >> 8; int rem = k & 255; int i = rem >> 4; int j = rem & 15;
    float v = x[(((size_t)b * 3 + c) * 224 + py * 16 + i) * 224 + px * 16 + j];
    bsplit(v, &dst[k], &dst[768 + k]);
  }
}

__global__ void assemble_kernel(const float* __restrict__ PE, const float* __restrict__ cls,
                                const float* __restrict__ pos, float* __restrict__ X) {
  int t = blockIdx.x, b = blockIdx.y; int tid = threadIdx.x;
  float* xp = X + ((size_t)(b * TMAX) + t) * D;
  for (int k = tid; k < D; k += 256) {
    float v = (t == 0) ? cls[k] : PE[((size_t)(b * NPATCH) + (t - 1)) * D + k];
    xp[k] = v + pos[(size_t)t * D + k];
  }
}

// ---------------- layernorm ----------------

__global__ void ln_kernel(const float* __restrict__ Xin, short* __restrict__ XNpk,
                          const float* __restrict__ wgt, const float* __restrict__ bsh,
                          const int* __restrict__ si) {
  int row = blockIdx.x;
  if ((row % TMAX) >= si[0]) return;
  __shared__ float red[256];
  int tid = threadIdx.x;
  const float* xp = Xin + (size_t)row * D;
  float v0 = xp[tid], v1 = xp[tid + 256], v2 = xp[tid + 512];
  float mu = block_reduce_sum(v0 + v1 + v2, red, tid) * (1.0f / 768.0f);
  float d0 = v0 - mu, d1 = v1 - mu, d2 = v2 - mu;
  float var = block_reduce_sum(d0 * d0 + d1 * d1 + d2 * d2, red, tid) * (1.0f / 768.0f);
  float inv = 1.0f / sqrtf(var + EPSF);
  short* op = XNpk + (size_t)row * 1536;
  float y0 = d0 * inv * wgt[tid] + bsh[tid];
  float y1 = d1 * inv * wgt[tid + 256] + bsh[tid + 256];
  float y2 = d2 * inv * wgt[tid + 512] + bsh[tid + 512];
  bsplit(y0, &op[tid], &op[768 + tid]);
  bsplit(y1, &op[tid + 256], &op[768 + tid + 256]);
  bsplit(y2, &op[tid + 512], &op[768 + tid + 512]);
}

__global__ void lnfinal_kernel(const float* __restrict__ X, float* __restrict__ CLSb,
                               const float* __restrict__ wgt, const float* __restrict__ bsh) {
  int b = blockIdx.x; int tid = threadIdx.x;
  __shared__ float red[256];
  const float* xp = X + (size_t)b * TMAX * D;  // row t=0
  float v0 = xp[tid], v1 = xp[tid + 256], v2 = xp[tid + 512];
  float mu = block_reduce_sum(v0 + v1 + v2, red, tid) * (1.0f / 768.0f);
  float d0 = v0 - mu, d1 = v1 - mu, d2 = v2 - mu;
  float var = block_reduce_sum(d0 * d0 + d1 * d1 + d2 * d2, red, tid) * (1.0f / 768.0f);
  float inv = 1.0f / sqrtf(var + EPSF);
  float* op = CLSb + (size_t)b * D;
  op[tid]       = d0 * inv * wgt[tid]       + bsh[tid];
  op[tid + 256] = d1 * inv * wgt[tid + 256] + bsh[tid + 256];
  op[tid + 512] = d2 * inv * wgt[tid + 512] + bsh[tid + 512];
}

// ---------- block-index swizzle ----------
__device__ __forceinline__ void swz_map(int d, int nx, int ny, int wsub,
                                        int& bx, int& by) {
  int q = ny >> 3, r = ny & 7;
  int rows, mb, l;
  int big = (q + 1) * nx;
  if (d < r * big) { int c = d / big; l = d - c * big; rows = q + 1; mb = c * (q + 1); }
  else { int d2 = d - r * big; int sm = q * nx; int c2 = d2 / sm; l = d2 - c2 * sm; rows = q; mb = r * (q + 1) + c2 * q; }
  int wspan = wsub * rows;
  int j = l / wspan; int t = l - j * wspan;
  int ml = t / wsub; int dx = t - ml * wsub;
  bx = j * wsub + dx; by = mb + ml;
}

// ---------------- MFMA GEMM 128x128 (R3-proven: gll16 A+B, 64KB dbuf) ----------
// bf16x3 split emulation of f32. One __syncthreads per K-tile; prefetch of
// tile k+1 issued after barrier, drained by the next barrier. Best-measured
// structure across R3-R10 (6.48ms total). EPI: 0=f32 out, 1=+residual f32,
// 2=GELU+packed bf16, 3=packed bf16 (QKV producer: split moved from mattn
// staging into this epilogue -- same bits, zero extra bytes).

#define GTM 128
#define GTN 128
#define GTK 32

template<int EPI, int SWZ>
__global__ __launch_bounds__(256)
void mgemm_kernel(const short* __restrict__ Apk, const short* __restrict__ Bpk,
                  const float* __restrict__ bias, const float* __restrict__ Rsrc,
                  float* __restrict__ Cf, short* __restrict__ Cpk,
                  int M, int K, int N, int nx, int ny, int wsub) {
  __shared__ char lds[65536];  // 2 buffers x (A 16KB | B 16KB)
  const int tid = threadIdx.x;
  const int ln = tid & 63;
  const int wv = tid >> 6;
  const int wm = wv >> 1, wn = wv & 1;

  int bx, by;
  if (SWZ) swz_map(blockIdx.x, nx, ny, wsub, bx, by);
  else { bx = blockIdx.x % nx; by = blockIdx.x / nx; }

  const int m0 = by * GTM, n0 = bx * GTN;
  const int lm = ln & 15, kc = ln >> 4;
  const size_t rs = 2 * (size_t)K;

  f32x4 acc[4][4];
  f32x4 zv = {0.f, 0.f, 0.f, 0.f};
  #pragma unroll
  for (int i = 0; i < 4; ++i)
    #pragma unroll
    for (int j = 0; j < 4; ++j) acc[i][j] = zv;

  auto stage = [&](int k0, int buf) {
    char* base = lds + (buf << 15);
    #pragma unroll
    for (int i = 0; i < 4; ++i) {
      int s = (i << 8) + tid;          // physical 16B slot index
      int r = s >> 3;                  // row 0..127
      int sl = (s & 7) ^ (r & 7);      // logical slot (inverse swizzle)
      size_t eoff = (size_t)(sl >> 2) * K + (size_t)(k0 + ((sl & 3) << 3));
      int ldsoff = ((i << 8) + (tid & 192)) << 4;  // wave-uniform
      gll16(Apk + (size_t)(m0 + r) * rs + eoff, base + ldsoff);
      gll16(Bpk + (size_t)(n0 + r) * rs + eoff, base + 16384 + ldsoff);
    }
  };

  const int nk = K / GTK;
  stage(0, 0);
  for (int kt = 0; kt < nk; ++kt) {
    __syncthreads();                    // drains vmcnt -> staged tile visible
    if (kt + 1 < nk) stage((kt + 1) * GTK, (kt + 1) & 1);
    const char* pa = lds + ((kt & 1) << 15);
    const char* pb = pa + 16384;
    bf16x8 bh[4], bl[4];
    #pragma unroll
    for (int j = 0; j < 4; ++j) {
      int c = wn * 64 + j * 16 + lm;
      int bo = c * 128 + ((kc ^ (c & 7)) << 4);
      bh[j] = *(const bf16x8*)(pb + bo);
      bl[j] = *(const bf16x8*)(pb + (bo ^ 64));
    }
    #pragma unroll
    for (int i = 0; i < 4; ++i) {
      int r = wm * 64 + i * 16 + lm;
      int ao = r * 128 + ((kc ^ (r & 7)) << 4);
      bf16x8 ah = *(const bf16x8*)(pa + ao);
      bf16x8 al = *(const bf16x8*)(pa + (ao ^ 64));
      #pragma unroll
      for (int j = 0; j < 4; ++j) {
        acc[i][j] = __builtin_amdgcn_mfma_f32_16x16x32_bf16(ah, bh[j], acc[i][j], 0, 0, 0);
        acc[i][j] = __builtin_amdgcn_mfma_f32_16x16x32_bf16(ah, bl[j], acc[i][j], 0, 0, 0);
        acc[i][j] = __builtin_amdgcn_mfma_f32_16x16x32_bf16(al, bh[j], acc[i][j], 0, 0, 0);
      }
    }
  }

  // epilogue: C/D layout col = ln&15, row = (ln>>4)*4 + t
  #pragma unroll
  for (int i = 0; i < 4; ++i) {
    #pragma unroll
    for (int t = 0; t < 4; ++t) {
      int m = m0 + wm * 64 + i * 16 + kc * 4 + t;
      if (m >= M) continue;
      #pragma unroll
      for (int j = 0; j < 4; ++j) {
        int n = n0 + wn * 64 + j * 16 + lm;
        float v = acc[i][j][t] + bias[n];
        if (EPI == 1) v += Rsrc[(size_t)m * N + n];
        if (EPI == 2 || EPI == 3) {
          if (EPI == 2) v = v * 0.5f * (1.0f + erff(v * 0.70710678118654752f));
          short h = f2bf(v);
          Cpk[(size_t)m * 2 * N + n] = h;
          Cpk[(size_t)m * 2 * N + N + n] = f2bf(v - bf2f(h));
        } else {
          Cf[(size_t)m * N + n] = v;
        }
      }
    }
  }
}

// ---------------- f32 GEMM (head only) ----------------

#define BM 128
#define BN 64
#define BK 16

__global__ __launch_bounds__(256, 2)
void gemm_kernel(const float* __restrict__ A, const float* __restrict__ Bw,
                 const float* __restrict__ bias, float* __restrict__ C,
                 int M, int K, int N) {
  __shared__ float As[BK][BM + 4];
  __shared__ float Bs[BK][BN];
  int tid = threadIdx.x;
  int tx = tid & 15;
  int ty = tid >> 4;
  int m0 = blockIdx.y * BM;
  int n0 = blockIdx.x * BN;
  float acc[8][4];
  #pragma unroll
  for (int i = 0; i < 8; ++i)
    #pragma unroll
    for (int j = 0; j < 4; ++j) acc[i][j] = 0.f;
  const int lkA = tid & 15;
  const int lmA = tid >> 4;
  const int lnB = tid & 63;
  const int lkB = tid >> 6;
  for (int k0 = 0; k0 < K; k0 += BK) {
    #pragma unroll
    for (int r = 0; r < 8; ++r) {
      int ml = r * 16 + lmA;
      int m = m0 + ml;
      float va = 0.f;
      if (m < M) va = A[(size_t)m * K + k0 + lkA];
      As[lkA][ml] = va;
    }
    #pragma unroll
    for (int r = 0; r < 4; ++r) {
      int kk = r * 4 + lkB;
      int n = n0 + lnB;
      float vb = 0.f;
      if (n < N) vb = Bw[(size_t)(k0 + kk) * N + n];
      Bs[kk][lnB] = vb;
    }
    __syncthreads();
    #pragma unroll
    for (int kk = 0; kk < BK; ++kk) {
      const float4 b4 = *(const float4*)(&Bs[kk][tx * 4]);
      const float4 a0 = *(const float4*)(&As[kk][ty * 8]);
      const float4 a1 = *(const float4*)(&As[kk][ty * 8 + 4]);
      const float a[8] = {a0.x, a0.y, a0.z, a0.w, a1.x, a1.y, a1.z, a1.w};
      const float bb[4] = {b4.x, b4.y, b4.z, b4.w};
      #pragma unroll
      for (int i = 0; i < 8; ++i)
        #pragma unroll
        for (int j = 0; j < 4; ++j)
          acc[i][j] = fmaf(a[i], bb[j], acc[i][j]);
    }
    __syncthreads();
  }
  #pragma unroll
  for (int i = 0; i < 8; ++i) {
    int m = m0 + ty * 8 + i;
    if (m >= M) continue;
    #pragma unroll
    for (int j = 0; j < 4; ++j) {
      int n = n0 + tx * 4 + j;
      if (n >= N) continue;
      C[(size_t)m * N + n] = acc[i][j] + bias[n];
    }
  }
}

// ---------------- MFMA attention (flash, bf16x3 split) ----------------
// QKV now arrives PRE-SPLIT (packed hi/lo from the QKV GEMM epilogue):
// row layout [hi 2304 | lo 2304] shorts. Staging is pure short4 copies --
// the per-tile f2bf VALU chains (~100 ops/thread, duplicated 4x per head)
// are gone. Bits identical to the old in-kernel split.

#define QT 64
#define KVT 64

__global__ __launch_bounds__(256)
void mattn_kernel(const short* __restrict__ QKVpk, short* __restrict__ AOpk,
                  const int* __restrict__ si) {
  const int tok = si[0];
  const int bh = blockIdx.x; const int b = bh / NH, h = bh % NH;
  const int q0 = blockIdx.y * QT;
  if (q0 >= tok) return;
  __shared__ short Kh[4096], Kl[4096], Vth[4096], Vtl[4096];  // 8KB each
  __shared__ short Pb[8192];                                   // 4 waves x (hi 1024 | lo 1024)
  const int tid = threadIdx.x;
  const int l = tid & 63, w = tid >> 6;
  const int lm = l & 15, lg = l >> 4;

  // Q fragments: direct 16B loads from packed planes
  bf16x8 qh[2], ql[2];
  {
    int qrow = q0 + w * 16 + lm;
    if (qrow >= TMAX) qrow = TMAX - 1;
    const short* qp = QKVpk + (size_t)(b * TMAX + qrow) * QPK + h * DH + lg * 8;
    #pragma unroll
    for (int c = 0; c < 2; ++c) {
      qh[c] = __builtin_bit_cast(bf16x8, *(const sshort8*)(qp + c * 32));
      ql[c] = __builtin_bit_cast(bf16x8, *(const sshort8*)(qp + QSTRIDE + c * 32));
    }
  }

  float mrun[4], lrun[4];
  f32x4 oacc[4];
  f32x4 zv = {0.f, 0.f, 0.f, 0.f};
  #pragma unroll
  for (int t = 0; t < 4; ++t) { mrun[t] = -1e30f; lrun[t] = 0.f; }
  #pragma unroll
  for (int j = 0; j < 4; ++j) oacc[j] = zv;

  const int r0 = (tid >> 4) * 4;     // 0..60
  const int td4 = (tid & 15) * 4;    // 0..60

  for (int j0 = 0; j0 < tok; j0 += KVT) {
    // ---- stage K and V^T (pure copies, no conversion) ----
    {
      short vh[16], vl[16];
      #pragma unroll
      for (int i = 0; i < 4; ++i) {
        int gr = j0 + r0 + i; if (gr >= TMAX) gr = TMAX - 1;
        const short* bp = QKVpk + (size_t)(b * TMAX + gr) * QPK;
        short4 kh4 = *(const short4*)(bp + D + h * DH + td4);
        short4 kl4 = *(const short4*)(bp + D + QSTRIDE + h * DH + td4);
        int r = r0 + i;
        int so = r * 64 + (((td4 >> 3) ^ (r & 7)) << 3) + (td4 & 7);
        *(short4*)(Kh + so) = kh4;
        *(short4*)(Kl + so) = kl4;
        short4 vh4 = *(const short4*)(bp + 2 * D + h * DH + td4);
        short4 vl4 = *(const short4*)(bp + 2 * D + QSTRIDE + h * DH + td4);
        vh[i * 4 + 0] = vh4.x; vh[i * 4 + 1] = vh4.y; vh[i * 4 + 2] = vh4.z; vh[i * 4 + 3] = vh4.w;
        vl[i * 4 + 0] = vl4.x; vl[i * 4 + 1] = vl4.y; vl[i * 4 + 2] = vl4.z; vl[i * 4 + 3] = vl4.w;
      }
      #pragma unroll
      for (int dd = 0; dd < 4; ++dd) {
        int d = td4 + dd;
        short4 sh, sl;
        sh.x = vh[dd]; sh.y = vh[4 + dd]; sh.z = vh[8 + dd]; sh.w = vh[12 + dd];
        sl.x = vl[dd]; sl.y = vl[4 + dd]; sl.z = vl[8 + dd]; sl.w = vl[12 + dd];
        int so = d * 64 + (((r0 >> 3) ^ (d & 7)) << 3) + (r0 & 7);
        *(short4*)(Vth + so) = sh;
        *(short4*)(Vtl + so) = sl;
      }
    }
    __syncthreads();

    // ---- S = Q K^T (3-product split) ----
    f32x4 sacc[4];
    #pragma unroll
    for (int jk = 0; jk < 4; ++jk) sacc[jk] = zv;
    #pragma unroll
    for (int c = 0; c < 2; ++c) {
      #pragma unroll
      for (int jk = 0; jk < 4; ++jk) {
        int row = jk * 16 + lm;
        int so = row * 64 + (((c * 4 + lg) ^ (row & 7)) << 3);
        bf16x8 kbh = *(const bf16x8*)(Kh + so);
        bf16x8 kbl = *(const bf16x8*)(Kl + so);
        sacc[jk] = __builtin_amdgcn_mfma_f32_16x16x32_bf16(qh[c], kbh, sacc[jk], 0, 0, 0);
        sacc[jk] = __builtin_amdgcn_mfma_f32_16x16x32_bf16(qh[c], kbl, sacc[jk], 0, 0, 0);
        sacc[jk] = __builtin_amdgcn_mfma_f32_16x16x32_bf16(ql[c], kbh, sacc[jk], 0, 0, 0);
      }
    }

    // ---- online softmax ----
    float p[4][4];
    #pragma unroll
    for (int jk = 0; jk < 4; ++jk) {
      bool valid = (j0 + jk * 16 + lm) < tok;
      #pragma unroll
      for (int t = 0; t < 4; ++t)
        p[jk][t] = valid ? sacc[jk][t] * SCALE : -1e30f;
    }
    float mt[4], mnew[4], co[4], rsm[4];
    #pragma unroll
    for (int t = 0; t < 4; ++t) {
      mt[t] = fmaxf(fmaxf(p[0][t], p[1][t]), fmaxf(p[2][t], p[3][t]));
      #pragma unroll
      for (int off = 1; off < 16; off <<= 1)
        mt[t] = fmaxf(mt[t], __shfl_xor(mt[t], off, 16));
      mnew[t] = fmaxf(mrun[t], mt[t]);
      co[t] = expf(mrun[t] - mnew[t]);
      rsm[t] = 0.f;
    }
    #pragma unroll
    for (int jk = 0; jk < 4; ++jk)
      #pragma unroll
      for (int t = 0; t < 4; ++t) {
        p[jk][t] = expf(p[jk][t] - mnew[t]);
        rsm[t] += p[jk][t];
      }
    #pragma unroll
    for (int t = 0; t < 4; ++t) {
      #pragma unroll
      for (int off = 1; off < 16; off <<= 1)
        rsm[t] += __shfl_xor(rsm[t], off, 16);
      lrun[t] = lrun[t] * co[t] + rsm[t];
      mrun[t] = mnew[t];
    }
    #pragma unroll
    for (int jd = 0; jd < 4; ++jd)
      #pragma unroll
      for (int t = 0; t < 4; ++t) oacc[jd][t] *= co[t];

    // ---- P -> per-wave LDS (bf16 hi/lo, A-frag layout) ----
    short* Pw = Pb + w * 2048;
    #pragma unroll
    for (int jk = 0; jk < 4; ++jk)
      #pragma unroll
      for (int t = 0; t < 4; ++t) {
        int q = lg * 4 + t;
        int col = jk * 16 + lm;
        short hh = f2bf(p[jk][t]);
        short hl = f2bf(p[jk][t] - bf2f(hh));
        int so = q * 64 + (((col >> 3) ^ (q & 7)) << 3) + (col & 7);
        Pw[so] = hh;
        Pw[1024 + so] = hl;
      }

    // ---- PV (3-product split) ----
    #pragma unroll
    for (int c = 0; c < 2; ++c) {
      int aro = lm * 64 + (((c * 4 + lg) ^ (lm & 7)) << 3);
      bf16x8 pah = *(const bf16x8*)(Pw + aro);
      bf16x8 pal = *(const bf16x8*)(Pw + 1024 + aro);
      #pragma unroll
      for (int jd = 0; jd < 4; ++jd) {
        int d = jd * 16 + lm;
        int so = d * 64 + (((c * 4 + lg) ^ (d & 7)) << 3);
        bf16x8 vbh = *(const bf16x8*)(Vth + so);
        bf16x8 vbl = *(const bf16x8*)(Vtl + so);
        oacc[jd] = __builtin_amdgcn_mfma_f32_16x16x32_bf16(pah, vbh, oacc[jd], 0, 0, 0);
        oacc[jd] = __builtin_amdgcn_mfma_f32_16x16x32_bf16(pah, vbl, oacc[jd], 0, 0, 0);
        oacc[jd] = __builtin_amdgcn_mfma_f32_16x16x32_bf16(pal, vbh, oacc[jd], 0, 0, 0);
      }
    }
    __syncthreads();
  }

  // ---- store O (split bf16), rows masked to tok ----
  #pragma unroll
  for (int t = 0; t < 4; ++t) {
    int q = q0 + w * 16 + lg * 4 + t;
    if (q >= tok) continue;
    float inv = 1.0f / lrun[t];
    short* op = AOpk + (size_t)(b * TMAX + q) * 1536 + h * DH;
    #pragma unroll
    for (int jd = 0; jd < 4; ++jd) {
      int d = jd * 16 + lm;
      float y = oacc[jd][t] * inv;
      short hh = f2bf(y);
      op[d] = hh;
      op[768 + d] = f2bf(y - bf2f(hh));
    }
  }
}

// cls attention row per (b,h): reads packed QKV, reconstructs f32 = hi+lo
__global__ void clsrow_kernel(const short* __restrict__ QKVpk, float* __restrict__ Pcls,
                              const int* __restrict__ si) {
  int tok = si[0];
  int bh = blockIdx.x; int b = bh / NH, h = bh % NH;
  int tid = threadIdx.x;
  __shared__ float q[DH];
  __shared__ float red[256];
  if (tid < DH) {
    const short* qp = QKVpk + (size_t)(b * TMAX) * QPK + h * DH;
    q[tid] = bf2f(qp[tid]) + bf2f(qp[QSTRIDE + tid]);
  }
  __syncthreads();
  float sval = -1e30f;
  if (tid < tok) {
    const short* kp = QKVpk + ((size_t)(b * TMAX) + tid) * QPK + D + h * DH;
    float a = 0.f;
    #pragma unroll
    for (int dd = 0; dd < DH; ++dd)
      a = fmaf(q[dd], bf2f(kp[dd]) + bf2f(kp[QSTRIDE + dd]), a);
    sval = a * SCALE;
  }
  red[tid] = sval; __syncthreads();
  #pragma unroll
  for (int o = 128; o > 0; o >>= 1) { if (tid < o) red[tid] = fmaxf(red[tid], red[tid + o]); __syncthreads(); }
  float mx = red[0]; __syncthreads();
  float e = (tid < tok) ? expf(sval - mx) : 0.f;
  red[tid] = e; __syncthreads();
  #pragma unroll
  for (int o = 128; o > 0; o >>= 1) { if (tid < o) red[tid] += red[tid + o]; __syncthreads(); }
  if (tid < tok) Pcls[(size_t)bh * TMAX + tid] = e / red[0];
}

__global__ void aclsmean_kernel(const float* __restrict__ Pcls, float* __restrict__ Acls,
                                const int* __restrict__ si) {
  int tok = si[0]; int b = blockIdx.x; int tid = threadIdx.x;
  if (tid < tok) {
    float s = 0.f;
    #pragma unroll
    for (int h = 0; h < NH; ++h) s += Pcls[((size_t)b * NH + h) * TMAX + tid];
    Acls[b * TMAX + tid] = s * (1.0f / 12.0f);
  }
}

__global__ void vmean_kernel(const short* __restrict__ QKVpk, float* __restrict__ Vm,
                             const int* __restrict__ si) {
  int tok = si[0];
  int t = blockIdx.x, b = blockIdx.y;
  if (t >= tok) return;
  int d = threadIdx.x;  // 64
  const short* vp = QKVpk + ((size_t)(b * TMAX + t)) * QPK + 2 * D;
  float s = 0.f;
  #pragma unroll
  for (int h = 0; h < NH; ++h)
    s += bf2f(vp[h * DH + d]) + bf2f(vp[QSTRIDE + h * DH + d]);
  Vm[((size_t)b * TMAX + t) * DH + d] = s * (1.0f / 12.0f);
}

// ---------------- pruning stats ----------------

__global__ void stats_kernel(const float* __restrict__ Vm, const float* __restrict__ Acls,
                             float* __restrict__ Jbuf, float* __restrict__ Jsum,
                             float* __restrict__ rhot, const int* __restrict__ si) {
  int tok = si[0]; int N = tok - 1;
  if (N <= 16) return;
  int b = blockIdx.x; int tid = threadIdx.x;
  __shared__ float red[256];
  __shared__ float vmean[DH];
  __shared__ float Vn[NPATCH];
  const float* vb = Vm + (size_t)b * TMAX * DH;

  float x0 = 0.f;
  if (tid < DH) { float v = vb[tid]; x0 = v * v; }
  red[tid] = x0; __syncthreads();
  #pragma unroll
  for (int o = 128; o > 0; o >>= 1) { if (tid < o) red[tid] += red[tid + o]; __syncthreads(); }
  if (tid == 0) rhot[b] = 1.0f + Acls[b * TMAX] * sqrtf(red[0]);
  __syncthreads();

  int d = tid & 63, part = tid >> 6;
  float s = 0.f;
  for (int t = 1 + part; t <= N; t += 4) s += vb[(size_t)t * DH + d];
  red[tid] = s; __syncthreads();
  if (tid < DH) vmean[tid] = (red[tid] + red[tid + 64] + red[tid + 128] + red[tid + 192]) / (float)N;
  __syncthreads();

  if (tid < N) {
    const float* vp = vb + (size_t)(tid + 1) * DH;
    float a = 0.f;
    #pragma unroll
    for (int dd = 0; dd < DH; ++dd) { float z = vp[dd] - vmean[dd]; a = fmaf(z, z, a); }
    Vn[tid] = sqrtf(a);
  }
  __syncthreads();

  red[tid] = (tid < N) ? Vn[tid] : 0.f; __syncthreads();
  #pragma unroll
  for (int o = 128; o > 0; o >>= 1) { if (tid < o) red[tid] += red[tid + o]; __syncthreads(); }
  float mu = red[0] / (float)N;
  __syncthreads();
  float dv = (tid < N) ? (Vn[tid] - mu) : 0.f;
  red[tid] = dv * dv; __syncthreads();
  #pragma unroll
  for (int o = 128; o > 0; o >>= 1) { if (tid < o) red[tid] += red[tid + o]; __syncthreads(); }
  float sd = sqrtf(red[0] / (float)(N - 1));
  __syncthreads();

  float Jv = 0.f;
  if (tid < N) {
    float z = (Vn[tid] - mu) / (sd + EPSF);
    z = fmaxf(z, 0.f);
    Jv = Acls[b * TMAX + 1 + tid] * z;
    Jbuf[b * NPATCH + tid] = Jv;
  }
  red[tid] = Jv; __syncthreads();
  #pragma unroll
  for (int o = 128; o > 0; o >>= 1) { if (tid < o) red[tid] += red[tid + o]; __syncthreads(); }
  if (tid == 0) Jsum[b] = red[0];
}

__global__ void decide_kernel(const float* __restrict__ Jbuf, const float* __restrict__ Jsum,
                              const float* __restrict__ rhot, int* __restrict__ keep,
                              int* __restrict__ si, float* __restrict__ sf) {
  int tok = si[0]; int N = tok - 1;
  int tid = threadIdx.x;
  if (N <= 16) { if (tid == 0) si[2] = 0; return; }
  __shared__ float red[256];
  __shared__ float Jms[NPATCH];
  __shared__ int sel[NPATCH];

  red[tid] = (tid < BATCH) ? rhot[tid] : 0.f; __syncthreads();
  #pragma unroll
  for (int o = 128; o > 0; o >>= 1) { if (tid < o) red[tid] += red[tid + o]; __syncthreads(); }
  float rho = red[0] / (float)BATCH; __syncthreads();
  red[tid] = (tid < BATCH) ? Jsum[tid] : 0.f; __syncthreads();
  #pragma unroll
  for (int o = 128; o > 0; o >>= 1) { if (tid < o) red[tid] += red[tid + o]; __syncthreads(); }
  float mass = red[0] / (float)BATCH;
  int prev_valid = si[1];
  float prev = sf[0];
  __syncthreads();

  int N_next = N;
  if (prev_valid) {
    float eta = mass / (prev + EPSF);
    float re = rho * eta;
    re = fminf(fmaxf(re, 0.25f), 4.0f);
    double kr = pow((double)re, -0.01);
    int nn = (int)((double)N * kr);
    N_next = nn > 16 ? nn : 16;
  }
  if (tid == 0) { si[1] = 1; sf[0] = mass; }

  if (N_next < N) {
    if (tid < N) {
      float sJ = 0.f;
      for (int bb = 0; bb < BATCH; ++bb) sJ += Jbuf[bb * NPATCH + tid];
      Jms[tid] = sJ / (float)BATCH;
    }
    __syncthreads();
    if (tid < N) {
      float me = Jms[tid]; int rank = 0;
      for (int s2 = 0; s2 < N; ++s2) {
        float ov = Jms[s2];
        if (ov > me || (ov == me && s2 < tid)) ++rank;
      }
      sel[tid] = (rank < N_next) ? 1 : 0;
    }
    __syncthreads();
    if (tid == 0) {
      int c = 0; keep[c++] = 0;
      for (int t2 = 0; t2 < N; ++t2) if (sel[t2]) keep[c++] = t2 + 1;
      si[0] = N_next + 1;
      si[2] = 1;
    }
  } else {
    if (tid == 0) si[2] = 0;
  }
}

__global__ void gather_kernel(const float* __restrict__ X, float* __restrict__ T,
                              const int* __restrict__ keep, const int* __restrict__ si) {
  if (!si[2]) return;
  int tok = si[0];
  int i = blockIdx.x, b = blockIdx.y;
  if (i >= tok) return;
  int src = keep[i];
  const float* xp = X + ((size_t)(b * TMAX) + src) * D;
  float* tp = T + ((size_t)(b * TMAX) + i) * D;
  int tid = threadIdx.x;
  tp[tid] = xp[tid]; tp[tid + 256] = xp[tid + 256]; tp[tid + 512] = xp[tid + 512];
}

__global__ void copyback_kernel(const float* __restrict__ T, float* __restrict__ X,
                                const int* __restrict__ si) {
  if (!si[2]) return;
  int tok = si[0];
  int i = blockIdx.x, b = blockIdx.y;
  if (i >= tok) return;
  const float* tp = T + ((size_t)(b * TMAX) + i) * D;
  float* xp = X + ((size_t)(b * TMAX) + i) * D;
  int tid = threadIdx.x;
  xp[tid] = tp[tid]; xp[tid + 256] = tp[tid + 256]; xp[tid + 512] = tp[tid + 512];
}

// ---------------- host ----------------

extern "C" void kernel_launch(void* const* d_in, const int* in_sizes, int n_in,
                              void* d_out, int out_size, void* d_ws, size_t ws_size,
                              hipStream_t stream) {
  (void)in_sizes; (void)n_in; (void)out_size;
  const float* x       = (const float*)d_in[0];
  const float* patch_w = (const float*)d_in[1];
  const float* patch_b = (const float*)d_in[2];
  const float* cls_tok = (const float*)d_in[3];
  const float* pos     = (const float*)d_in[4];
  const float* ln1w    = (const float*)d_in[5];
  const float* ln1b    = (const float*)d_in[6];
  const float* qkvw    = (const float*)d_in[7];
  const float* qkvb    = (const float*)d_in[8];
  const float* projw   = (const float*)d_in[9];
  const float* projb   = (const float*)d_in[10];
  const float* ln2w    = (const float*)d_in[11];
  const float* ln2b    = (const float*)d_in[12];
  const float* fc1w    = (const float*)d_in[13];
  const float* fc1b    = (const float*)d_in[14];
  const float* fc2w    = (const float*)d_in[15];
  const float* fc2b    = (const float*)d_in[16];
  const float* normw   = (const float*)d_in[17];
  const float* normb   = (const float*)d_in[18];
  const float* headw   = (const float*)d_in[19];
  const float* headb   = (const float*)d_in[20];
  float* out = (float*)d_out;

  char* w = (char*)d_ws;
  size_t off = 0;
  auto alloc = [&](size_t bytes) -> void* {
    void* p = w + off;
    off += (bytes + 255) & ~(size_t)255;
    return p;
  };
  const size_t MROWS = (size_t)BATCH * TMAX;  // 6304 (MPAD=6400 for staged A bufs)
  float* X     = (float*)alloc(MROWS * D * 4);
  short* XNpk  = (short*)alloc((size_t)MPAD * 1536 * 2);
  short* QKVpk = (short*)alloc(MROWS * QPK * 2);            // packed hi/lo QKV
  short* AOpk  = (short*)alloc((size_t)MPAD * 1536 * 2);
  short* Hpk   = (short*)alloc((size_t)MPAD * 2 * DFF * 2);  // also Impk / gather TMP
  float* Vm    = (float*)alloc(MROWS * DH * 4);
  float* Pcls  = (float*)alloc((size_t)BATCH * NH * TMAX * 4);
  float* Acls  = (float*)alloc((size_t)BATCH * TMAX * 4);
  float* Jbuf  = (float*)alloc((size_t)BATCH * NPATCH * 4);
  float* Jsum  = (float*)alloc(BATCH * 4);
  float* rhot  = (float*)alloc(BATCH * 4);
  int*   keep  = (int*)alloc(256 * 4);
  int*   si    = (int*)alloc(64 * 4);
  float* sf    = (float*)alloc(64 * 4);
  float* CLS   = (float*)alloc((size_t)BATCH * D * 4);
  short* Wq    = (short*)alloc((size_t)QSTRIDE * 2 * D * 2);
  short* Wp    = (short*)alloc((size_t)D * 2 * D * 2);
  short* W1    = (short*)alloc((size_t)DFF * 2 * D * 2);
  short* W2    = (short*)alloc((size_t)D * 2 * DFF * 2);
  short* Wpat  = (short*)alloc((size_t)D * 2 * D * 2);
  short* Impk  = Hpk;
  float* TMP   = (float*)Hpk;
  float* Ef32  = (float*)AOpk;   // free until mattn writes AOpk inside the loop

  if (off > ws_size) {
    fail_kernel<<<1, 1, 0, stream>>>(out);
    return;
  }

  init_kernel<<<1, 1, 0, stream>>>(si, sf);

  // patch embed (M = 6272 = 49*128 exactly)
  im2col_kernel<<<dim3(NPATCH, BATCH), 256, 0, stream>>>(x, Impk);
  wsplit_nt<<<D, 256, 0, stream>>>(patch_w, Wpat, D);
  mgemm_kernel<0, 1><<<6 * 49, 256, 0, stream>>>(
      Impk, Wpat, patch_b, nullptr, Ef32, nullptr, BATCH * NPATCH, D, D, 6, 49, 6);
  assemble_kernel<<<dim3(TMAX, BATCH), 256, 0, stream>>>(Ef32, cls_tok, pos, X);

  for (int l = 0; l < DEPTH; ++l) {
    const float* l1w = ln1w + l * D;
    const float* l1b = ln1b + l * D;
    const float* qw  = qkvw + (size_t)l * D * 3 * D;
    const float* qb  = qkvb + (size_t)l * 3 * D;
    const float* pw  = projw + (size_t)l * D * D;
    const float* pb  = projb + (size_t)l * D;
    const float* l2w = ln2w + l * D;
    const float* l2b = ln2b + l * D;
    const float* f1w = fc1w + (size_t)l * D * DFF;
    const float* f1b = fc1b + (size_t)l * DFF;
    const float* f2w = fc2w + (size_t)l * DFF * D;
    const float* f2b = fc2b + (size_t)l * D;

    wsplit_t<<<dim3(QSTRIDE / 32, D / 32), 256, 0, stream>>>(qw, Wq, D, QSTRIDE);
    wsplit_t<<<dim3(D / 32, D / 32), 256, 0, stream>>>(pw, Wp, D, D);
    wsplit_t<<<dim3(DFF / 32, D / 32), 256, 0, stream>>>(f1w, W1, D, DFF);
    wsplit_t<<<dim3(D / 32, DFF / 32), 256, 0, stream>>>(f2w, W2, DFF, D);

    ln_kernel<<<BATCH * TMAX, 256, 0, stream>>>(X, XNpk, l1w, l1b, si);
    // QKV GEMM writes packed hi/lo directly (EPI=3)
    mgemm_kernel<3, 1><<<18 * 50, 256, 0, stream>>>(
        XNpk, Wq, qb, nullptr, nullptr, QKVpk, (int)MROWS, D, QSTRIDE, 18, 50, 6);
    mattn_kernel<<<dim3(BATCH * NH, (TMAX + QT - 1) / QT), 256, 0, stream>>>(QKVpk, AOpk, si);
    clsrow_kernel<<<BATCH * NH, 256, 0, stream>>>(QKVpk, Pcls, si);
    aclsmean_kernel<<<BATCH, 256, 0, stream>>>(Pcls, Acls, si);
    vmean_kernel<<<dim3(TMAX, BATCH), 64, 0, stream>>>(QKVpk, Vm, si);
    mgemm_kernel<1, 1><<<6 * 50, 256, 0, stream>>>(
        AOpk, Wp, pb, X, X, nullptr, (int)MROWS, D, D, 6, 50, 6);
    ln_kernel<<<BATCH * TMAX, 256, 0, stream>>>(X, XNpk, l2w, l2b, si);
    mgemm_kernel<2, 1><<<24 * 50, 256, 0, stream>>>(
        XNpk, W1, f1b, nullptr, nullptr, Hpk, (int)MROWS, D, DFF, 24, 50, 8);
    mgemm_kernel<1, 0><<<6 * 50, 256, 0, stream>>>(
        Hpk, W2, f2b, X, X, nullptr, (int)MROWS, DFF, D, 6, 50, 6);
    stats_kernel<<<BATCH, 256, 0, stream>>>(Vm, Acls, Jbuf, Jsum, rhot, si);
    decide_kernel<<<1, 256, 0, stream>>>(Jbuf, Jsum, rhot, keep, si, sf);
    gather_kernel<<<dim3(TMAX, BATCH), 256, 0, stream>>>(X, TMP, keep, si);
    copyback_kernel<<<dim3(TMAX, BATCH), 256, 0, stream>>>(TMP, X, si);
  }

  lnfinal_kernel<<<BATCH, 256, 0, stream>>>(X, CLS, normw, normb);
  gemm_kernel<<<dim3(16, 1), 256, 0, stream>>>(CLS, headw, headb, out, BATCH, D, NC);
}